// Round 8
// baseline (159.943 us; speedup 1.0000x reference)
//
#include <hip/hip_runtime.h>
#include <stdint.h>

#define TT 131072
#define MD 8
#define CHUNK 32
#define NCH 1024
#define RMP 72   // row-major LDS pad (shorts per row)

using f32x4  = __attribute__((ext_vector_type(4))) float;
using bf16x8 = __attribute__((ext_vector_type(8))) __bf16;
using u32x2  = __attribute__((ext_vector_type(2))) uint32_t;
using u32x4  = __attribute__((ext_vector_type(4))) uint32_t;

// log(n!) for n = 0..19 (x in [0,20))
__device__ __constant__ float c_lg[20] = {
    0.0f, 0.0f, 0.69314718f, 1.79175947f, 3.17805383f,
    4.78749174f, 6.57925121f, 8.52516136f, 10.60460290f, 12.80182748f,
    15.10441257f, 17.50230785f, 19.98721386f, 22.55216385f, 25.19122118f,
    27.89927138f, 30.67186011f, 33.50507345f, 36.39544521f, 39.33988419f};

#define MFMA(a, b, c) __builtin_amdgcn_mfma_f32_16x16x32_bf16((a), (b), (c), 0, 0, 0)

// Bookkeeping fragment map sigma (consistent everywhere; HW map may differ —
// it cancels): frag elem e of a K=32 operand covers k = 16*(e>>2) + 4*q + (e&3),
// q = lane>>4; A rows / B cols on lane&15. State B[kf][nb] holds
// M[32kf + sigma(l,e)][16nb + (l&15)].

// full emission (K3 only): pe = exp(g-gmax), gs = gmax - sum lgamma(x+1)
__device__ __forceinline__ void emis(const int4& xa, const int4& xb,
                                     const float* ll, float lamsum,
                                     const float* lgt, float& pe, float& gs) {
    float g = -lamsum;
    g = fmaf((float)xa.x, ll[0], g);
    g = fmaf((float)xa.y, ll[1], g);
    g = fmaf((float)xa.z, ll[2], g);
    g = fmaf((float)xa.w, ll[3], g);
    g = fmaf((float)xb.x, ll[4], g);
    g = fmaf((float)xb.y, ll[5], g);
    g = fmaf((float)xb.z, ll[6], g);
    g = fmaf((float)xb.w, ll[7], g);
    float Lt = lgt[xa.x] + lgt[xa.y] + lgt[xa.z] + lgt[xa.w] +
               lgt[xb.x] + lgt[xb.y] + lgt[xb.z] + lgt[xb.w];
    float gm = g;
#pragma unroll
    for (int m = 1; m <= 32; m <<= 1) gm = fmaxf(gm, __shfl_xor(gm, m, 64));
    pe = __expf(g - gm);
    gs = gm - Lt;
}

// loop emission: no lgamma (hoisted); gm_out = gmax only
__device__ __forceinline__ void emis_ng(const int4& xa, const int4& xb,
                                        const float* ll, float lamsum,
                                        float& pe, float& gm_out) {
    float g = -lamsum;
    g = fmaf((float)xa.x, ll[0], g);
    g = fmaf((float)xa.y, ll[1], g);
    g = fmaf((float)xa.z, ll[2], g);
    g = fmaf((float)xa.w, ll[3], g);
    g = fmaf((float)xb.x, ll[4], g);
    g = fmaf((float)xb.y, ll[5], g);
    g = fmaf((float)xb.z, ll[6], g);
    g = fmaf((float)xb.w, ll[7], g);
    float gm = g;
#pragma unroll
    for (int m = 1; m <= 32; m <<= 1) gm = fmaxf(gm, __shfl_xor(gm, m, 64));
    pe = __expf(g - gm);
    gm_out = gm;
}

// ---- fragment <-> memory helpers (map sigma; verified R4) ----

__device__ __forceinline__ void identity_B(bf16x8 B[2][4], int li, int q) {
#pragma unroll
    for (int kf = 0; kf < 2; ++kf)
#pragma unroll
        for (int nb = 0; nb < 4; ++nb) {
            int n = 16 * nb + li;
            u32x4 u;
#pragma unroll
            for (int wi = 0; wi < 4; ++wi) {
                int k0 = 32 * kf + 16 * (wi >> 1) + 4 * q + 2 * (wi & 1);
                uint32_t v = 0;
                if (k0 == n) v |= 0x3F80u;
                if (k0 + 1 == n) v |= 0x3F800000u;
                u[wi] = v;
            }
            B[kf][nb] = __builtin_bit_cast(bf16x8, u);
        }
}

// scatter state regs -> LDS row-major [k][n] pad RMP
__device__ __forceinline__ void state_to_rm(short* rm, const bf16x8 B[2][4],
                                            int li, int q) {
#pragma unroll
    for (int kf = 0; kf < 2; ++kf)
#pragma unroll
        for (int nb = 0; nb < 4; ++nb) {
            u32x4 u = __builtin_bit_cast(u32x4, B[kf][nb]);
            int n = 16 * nb + li;
#pragma unroll
            for (int wi = 0; wi < 4; ++wi) {
                int k0 = 32 * kf + 16 * (wi >> 1) + 4 * q + 2 * (wi & 1);
                uint32_t v = u[wi];
                rm[k0 * RMP + n] = (short)(v & 0xFFFFu);
                rm[(k0 + 1) * RMP + n] = (short)(v >> 16);
            }
        }
}

// scatter state regs -> GLOBAL row-major [k][n] stride 64
__device__ __forceinline__ void dump_rm_g(short* gm, const bf16x8 B[2][4],
                                          int li, int q) {
#pragma unroll
    for (int kf = 0; kf < 2; ++kf)
#pragma unroll
        for (int nb = 0; nb < 4; ++nb) {
            u32x4 u = __builtin_bit_cast(u32x4, B[kf][nb]);
            int n = 16 * nb + li;
#pragma unroll
            for (int wi = 0; wi < 4; ++wi) {
                int k0 = 32 * kf + 16 * (wi >> 1) + 4 * q + 2 * (wi & 1);
                uint32_t v = u[wi];
                gm[k0 * 64 + n] = (short)(v & 0xFFFFu);
                gm[(k0 + 1) * 64 + n] = (short)(v >> 16);
            }
        }
}

// read A-frags from LDS row-major [m][k] pad RMP
__device__ __forceinline__ void load_afrags(const short* rm, int li, int q,
                                            bf16x8 A[4][2]) {
#pragma unroll
    for (int mb = 0; mb < 4; ++mb)
#pragma unroll
        for (int kf = 0; kf < 2; ++kf) {
            const short* p = rm + (16 * mb + li) * RMP + 32 * kf + 4 * q;
            u32x2 lo = *(const u32x2*)p;
            u32x2 hi = *(const u32x2*)(p + 16);
            u32x4 u = {lo[0], lo[1], hi[0], hi[1]};
            A[mb][kf] = __builtin_bit_cast(bf16x8, u);
        }
}

// read A-frags from GLOBAL row-major [m][k] stride 64
__device__ __forceinline__ void load_afrags_g(const short* gm, int li, int q,
                                              bf16x8 A[4][2]) {
#pragma unroll
    for (int mb = 0; mb < 4; ++mb)
#pragma unroll
        for (int kf = 0; kf < 2; ++kf) {
            const short* p = gm + (16 * mb + li) * 64 + 32 * kf + 4 * q;
            u32x2 lo = *(const u32x2*)p;
            u32x2 hi = *(const u32x2*)(p + 16);
            u32x4 u = {lo[0], lo[1], hi[0], hi[1]};
            A[mb][kf] = __builtin_bit_cast(bf16x8, u);
        }
}

// B <- normalize(A*B); returns applied max. Caller logs it exactly.
__device__ __forceinline__ float leftmul(const bf16x8 A[4][2], bf16x8 B[2][4]) {
    f32x4 d[4][4];
#pragma unroll
    for (int mb = 0; mb < 4; ++mb)
#pragma unroll
        for (int nb = 0; nb < 4; ++nb) {
            f32x4 z = {0.f, 0.f, 0.f, 0.f};
            d[mb][nb] = MFMA(A[mb][0], B[0][nb], z);
            d[mb][nb] = MFMA(A[mb][1], B[1][nb], d[mb][nb]);
        }
    float pm = 0.f;
#pragma unroll
    for (int mb = 0; mb < 4; ++mb)
#pragma unroll
        for (int nb = 0; nb < 4; ++nb)
            pm = fmaxf(pm, fmaxf(fmaxf(d[mb][nb][0], d[mb][nb][1]),
                                 fmaxf(d[mb][nb][2], d[mb][nb][3])));
#pragma unroll
    for (int m = 1; m <= 32; m <<= 1) pm = fmaxf(pm, __shfl_xor(pm, m, 64));
    pm = fmaxf(pm, 1e-30f);
    float r = 1.0f / pm;
#pragma unroll
    for (int mb = 0; mb < 4; ++mb)
#pragma unroll
        for (int nb = 0; nb < 4; ++nb) {
#pragma unroll
            for (int reg = 0; reg < 4; ++reg)
                B[mb >> 1][nb][(mb & 1) * 4 + reg] =
                    (__bf16)(d[mb][nb][reg] * r);
        }
    return pm;
}

// One scan step (R6-verified semantics): BOUT <- diag(pe_s)*T*BIN / NRMV,
// NRMV = post-scale max from 2 steps ago (exact f64 bookkeeping of applied
// factor). pm computed on POST-scale values (self-normalizing, stable).
// Pipelined: emission for s+1 into pes[WS]/GSN; x prefetch s+2.
#define STEP(BIN, BOUT, RS, WS, NRMV, GSC, GSN)                              \
    {                                                                        \
        int tn = t0 + s + 2;                                                 \
        tn = tn > TT - 1 ? TT - 1 : tn;                                      \
        int4 xan = *(const int4*)(x + (size_t)tn * MD);                      \
        int4 xbn = *(const int4*)(x + (size_t)tn * MD + 4);                  \
        float pe_n, gm_n;                                                    \
        emis_ng(xa1, xb1, ll, lamsum, pe_n, gm_n);                           \
        GSN = gm_n;                                                          \
        pes[WS][w][l] = pe_n;                                                \
        float r = 1.0f / NRMV;                                               \
        S += (double)GSC + (double)__logf(NRMV);                             \
        const float* pc = &pes[RS][w][0];                                    \
        float pm = 0.f;                                                      \
        _Pragma("unroll") for (int mb = 0; mb < 4; ++mb) {                   \
            f32x4 d[4];                                                      \
            _Pragma("unroll") for (int nb = 0; nb < 4; ++nb) {               \
                f32x4 z = {0.f, 0.f, 0.f, 0.f};                              \
                d[nb] = MFMA(TA[mb][0], BIN[0][nb], z);                      \
                d[nb] = MFMA(TA[mb][1], BIN[1][nb], d[nb]);                  \
            }                                                                \
            float4 sc = *(const float4*)(pc + 16 * mb + 4 * q);              \
            float s0 = sc.x * r, s1 = sc.y * r;                              \
            float s2 = sc.z * r, s3 = sc.w * r;                              \
            _Pragma("unroll") for (int nb = 0; nb < 4; ++nb) {               \
                float v0 = d[nb][0] * s0;                                    \
                float v1 = d[nb][1] * s1;                                    \
                float v2 = d[nb][2] * s2;                                    \
                float v3 = d[nb][3] * s3;                                    \
                pm = fmaxf(pm, fmaxf(fmaxf(v0, v1), fmaxf(v2, v3)));         \
                BOUT[mb >> 1][nb][(mb & 1) * 4 + 0] = (__bf16)v0;            \
                BOUT[mb >> 1][nb][(mb & 1) * 4 + 1] = (__bf16)v1;            \
                BOUT[mb >> 1][nb][(mb & 1) * 4 + 2] = (__bf16)v2;            \
                BOUT[mb >> 1][nb][(mb & 1) * 4 + 3] = (__bf16)v3;            \
            }                                                                \
        }                                                                    \
        _Pragma("unroll") for (int m = 1; m <= 32; m <<= 1)                  \
            pm = fmaxf(pm, __shfl_xor(pm, m, 64));                           \
        NRMV = fmaxf(pm, 1e-30f);                                            \
        xa1 = xan;                                                           \
        xb1 = xbn;                                                           \
        ++s;                                                                 \
    }

// ---------------- K1: per-chunk transfer-matrix product, in-register --------
__global__ __launch_bounds__(256, 2) void k_chunks(
    const int* __restrict__ x, const float* __restrict__ lambdas,
    const float* __restrict__ logT, short* __restrict__ M1,
    double* __restrict__ S1) {
    __shared__ short rm[4][64 * RMP];
    __shared__ float pes[2][4][64];
    __shared__ float lgt[20];
    __shared__ double Sw[4];
    const int tid = threadIdx.x;
    const int l = tid & 63, w = tid >> 6;
    const int li = l & 15, q = l >> 4;
    if (tid < 20) lgt[tid] = c_lg[tid];

    float ll[8];
    float lamsum = 0.f;
#pragma unroll
    for (int m = 0; m < 8; ++m) {
        float lam = lambdas[l * 8 + m];
        ll[m] = __logf(lam);
        lamsum += lam;
    }

    // constant A-frags of T: elem e of TA[mb][kf] = T[16mb+li][32kf+sigma(l,e)]
    bf16x8 TA[4][2];
#pragma unroll
    for (int mb = 0; mb < 4; ++mb)
#pragma unroll
        for (int kf = 0; kf < 2; ++kf) {
            const float* tp = logT + (16 * mb + li) * 64 + 32 * kf + 4 * q;
            float4 v0 = *(const float4*)tp;
            float4 v1 = *(const float4*)(tp + 16);
            bf16x8 a;
            a[0] = (__bf16)__expf(v0.x);
            a[1] = (__bf16)__expf(v0.y);
            a[2] = (__bf16)__expf(v0.z);
            a[3] = (__bf16)__expf(v0.w);
            a[4] = (__bf16)__expf(v1.x);
            a[5] = (__bf16)__expf(v1.y);
            a[6] = (__bf16)__expf(v1.z);
            a[7] = (__bf16)__expf(v1.w);
            TA[mb][kf] = a;
        }

    bf16x8 B0[2][4], B1[2][4];
    identity_B(B0, li, q);
    __syncthreads();  // lgt visible

    const int c = blockIdx.x * 4 + w;
    const int t0 = 1 + c * CHUNK;
    const int len = min(CHUNK, TT - t0);

    double S = 0.0;
    float nA = 1.0f, nBv = 1.0f;   // nrm ring: nrm_{s-2} (even/odd slots)
    float gsA = 0.f, gsB = 0.f;    // pipelined gmax ring
    int4 xa1, xb1;
    {
        int4 xa0 = *(const int4*)(x + (size_t)t0 * MD);
        int4 xb0 = *(const int4*)(x + (size_t)t0 * MD + 4);
        int t1 = t0 + 1 > TT - 1 ? TT - 1 : t0 + 1;
        xa1 = *(const int4*)(x + (size_t)t1 * MD);
        xb1 = *(const int4*)(x + (size_t)t1 * MD + 4);
        float pe0;
        emis_ng(xa0, xb0, ll, lamsum, pe0, gsA);
        pes[0][w][l] = pe0;
    }

    int s = 0;
    const int np = len >> 1;
#pragma unroll 1
    for (int p = 0; p < np; ++p) {
        STEP(B0, B1, 0, 1, nA, gsA, gsB);
        STEP(B1, B0, 1, 0, nBv, gsB, gsA);
    }
    if (len & 1) {
        STEP(B0, B1, 0, 1, nA, gsA, gsB);
#pragma unroll
        for (int kf = 0; kf < 2; ++kf)
#pragma unroll
            for (int nb = 0; nb < 4; ++nb) B0[kf][nb] = B1[kf][nb];
    }

    // hoisted lgamma: Sigma_t lgamma(x[t]+1), lane-parallel over t
    {
        float lt = 0.f;
        if (l < len) {
            const int4* xp = (const int4*)(x + (size_t)(t0 + l) * MD);
            int4 a = xp[0], b = xp[1];
            lt = lgt[a.x] + lgt[a.y] + lgt[a.z] + lgt[a.w] + lgt[b.x] +
                 lgt[b.y] + lgt[b.z] + lgt[b.w];
        }
#pragma unroll
        for (int m = 1; m <= 32; m <<= 1) lt += __shfl_xor(lt, m, 64);
        S -= (double)lt;
    }

    // ---- block combine: product = M3*M2*M1*M0, dump row-major ----
    if (w) state_to_rm(&rm[w][0], B0, li, q);
    if (l == 0) Sw[w] = S;
    __syncthreads();
    if (w == 0) {
#pragma unroll 1
        for (int j = 1; j < 4; ++j) {
            bf16x8 A[4][2];
            load_afrags(&rm[j][0], li, q, A);
            float pm = leftmul(A, B0);
            S += Sw[j] + (double)__logf(pm);
        }
        dump_rm_g(M1 + (size_t)blockIdx.x * 4096, B0, li, q);
        if (l == 0) S1[blockIdx.x] = S;
    }
}

// ---------------- K2: fold 1024 -> 16 ---------------------------------------
__global__ __launch_bounds__(256, 1) void k_combine(
    const short* __restrict__ M1, const double* __restrict__ S1,
    short* __restrict__ M2, double* __restrict__ S2) {
    __shared__ short rm[4][64 * RMP];
    __shared__ double Sw[4];
    const int tid = threadIdx.x;
    const int l = tid & 63, w = tid >> 6;
    const int li = l & 15, q = l >> 4;
    const int base = blockIdx.x * 64 + w * 16;

    bf16x8 B[2][4];
    identity_B(B, li, q);
    double S = 0.0;

#pragma unroll 1
    for (int j = 0; j < 16; ++j) {
        bf16x8 A[4][2];
        load_afrags_g(M1 + (size_t)(base + j) * 4096, li, q, A);
        float pm = leftmul(A, B);
        S += S1[base + j] + (double)__logf(pm);
    }

    if (w) state_to_rm(&rm[w][0], B, li, q);
    if (l == 0) Sw[w] = S;
    __syncthreads();
    if (w == 0) {
#pragma unroll 1
        for (int j = 1; j < 4; ++j) {
            bf16x8 A[4][2];
            load_afrags(&rm[j][0], li, q, A);
            float pm = leftmul(A, B);
            S += Sw[j] + (double)__logf(pm);
        }
        dump_rm_g(M2 + (size_t)blockIdx.x * 4096, B, li, q);
        if (l == 0) S2[blockIdx.x] = S;
    }
}

// ---------------- K3: fold 16 -> 1, alpha0, final LSE ------------------------
__global__ __launch_bounds__(256, 1) void k_final(
    const int* __restrict__ x, const float* __restrict__ lambdas,
    const float* __restrict__ prior, const short* __restrict__ M2,
    const double* __restrict__ S2, float* __restrict__ out) {
    __shared__ short rm[4][64 * RMP];
    __shared__ double Sw[4];
    __shared__ float lgt[20];
    const int tid = threadIdx.x;
    const int l = tid & 63, w = tid >> 6;
    const int li = l & 15, q = l >> 4;
    if (tid < 20) lgt[tid] = c_lg[tid];
    __syncthreads();

    bf16x8 B[2][4];
    identity_B(B, li, q);
    double S = 0.0;

#pragma unroll 1
    for (int j = 0; j < 4; ++j) {
        int idx = w * 4 + j;
        bf16x8 A[4][2];
        load_afrags_g(M2 + (size_t)idx * 4096, li, q, A);
        float pm = leftmul(A, B);
        S += S2[idx] + (double)__logf(pm);
    }

    if (w) state_to_rm(&rm[w][0], B, li, q);
    if (l == 0) Sw[w] = S;
    __syncthreads();
    if (w == 0) {
#pragma unroll 1
        for (int j = 1; j < 4; ++j) {
            bf16x8 A[4][2];
            load_afrags(&rm[j][0], li, q, A);
            float pm = leftmul(A, B);
            S += Sw[j] + (double)__logf(pm);
        }
        // finalize: alpha0 = em_0 * exp(prior); total = 1^T B alpha0
        float ll[8];
        float lamsum = 0.f;
#pragma unroll
        for (int m = 0; m < 8; ++m) {
            float lam = lambdas[l * 8 + m];
            ll[m] = __logf(lam);
            lamsum += lam;
        }
        int4 xa = *(const int4*)(x);
        int4 xb = *(const int4*)(x + 4);
        float pe0, gs0;
        emis(xa, xb, ll, lamsum, lgt, pe0, gs0);
        S += (double)gs0;
        float a0 = pe0 * __expf(prior[l]);

        float av[4];
#pragma unroll
        for (int nb = 0; nb < 4; ++nb) av[nb] = __shfl(a0, 16 * nb + li, 64);

        float acc = 0.f;
#pragma unroll
        for (int kf = 0; kf < 2; ++kf)
#pragma unroll
            for (int nb = 0; nb < 4; ++nb) {
                u32x4 u = __builtin_bit_cast(u32x4, B[kf][nb]);
#pragma unroll
                for (int e = 0; e < 4; ++e) {
                    float flo = __builtin_bit_cast(float, u[e] << 16);
                    float fhi = __builtin_bit_cast(float, u[e] & 0xFFFF0000u);
                    acc = fmaf(flo + fhi, av[nb], acc);
                }
            }
#pragma unroll
        for (int m = 1; m <= 32; m <<= 1) acc += __shfl_xor(acc, m, 64);
        if (l == 0) out[0] = (float)(S + (double)__logf(acc));
    }
}

extern "C" void kernel_launch(void* const* d_in, const int* in_sizes, int n_in,
                              void* d_out, int out_size, void* d_ws,
                              size_t ws_size, hipStream_t stream) {
    const int* x = (const int*)d_in[0];
    const float* lambdas = (const float*)d_in[1];
    const float* logT = (const float*)d_in[2];
    const float* prior = (const float*)d_in[3];
    float* out = (float*)d_out;
    char* ws = (char*)d_ws;
    // ws layout (~8.53 MB): M1 1024*4096*2B, S1 1024*8B, M2 16*4096*2B, S2 16*8B
    short* M1 = (short*)ws;
    double* S1 = (double*)(ws + 8388608);
    short* M2 = (short*)(ws + 8396800);
    double* S2 = (double*)(ws + 8527872);

    k_chunks<<<NCH, 256, 0, stream>>>(x, lambdas, logT, M1, S1);
    k_combine<<<16, 256, 0, stream>>>(M1, S1, M2, S2);
    k_final<<<1, 256, 0, stream>>>(x, lambdas, prior, M2, S2, out);
}

// Round 9
// 145.824 us; speedup vs baseline: 1.0968x; 1.0968x over previous
//
#include <hip/hip_runtime.h>
#include <stdint.h>

#define TT 131072
#define MD 8
#define CHUNK 32
#define NCH 1024
#define RMP 72   // row-major LDS pad (shorts per row)

using f32x4  = __attribute__((ext_vector_type(4))) float;
using bf16x8 = __attribute__((ext_vector_type(8))) __bf16;
using bf16x2 = __attribute__((ext_vector_type(2))) __bf16;
using u32x2  = __attribute__((ext_vector_type(2))) uint32_t;
using u32x4  = __attribute__((ext_vector_type(4))) uint32_t;

// log(n!) for n = 0..19 (x in [0,20))
__device__ __constant__ float c_lg[20] = {
    0.0f, 0.0f, 0.69314718f, 1.79175947f, 3.17805383f,
    4.78749174f, 6.57925121f, 8.52516136f, 10.60460290f, 12.80182748f,
    15.10441257f, 17.50230785f, 19.98721386f, 22.55216385f, 25.19122118f,
    27.89927138f, 30.67186011f, 33.50507345f, 36.39544521f, 39.33988419f};

#define MFMA(a, b, c) __builtin_amdgcn_mfma_f32_16x16x32_bf16((a), (b), (c), 0, 0, 0)

// pack two f32 -> one u32 of 2 bf16 (RNE; compiler emits v_cvt_pk_bf16_f32)
__device__ __forceinline__ uint32_t pk2(float lo, float hi) {
    bf16x2 t = {(__bf16)lo, (__bf16)hi};
    return __builtin_bit_cast(uint32_t, t);
}

// Bookkeeping fragment map sigma (consistent everywhere; HW map may differ —
// it cancels): frag elem e of a K=32 operand covers k = 16*(e>>2) + 4*q + (e&3),
// q = lane>>4; A rows / B cols on lane&15. State B[kf][nb] holds
// M[32kf + sigma(l,e)][16nb + (l&15)].

// full emission (K3 only): pe = exp(g-gmax), gs = gmax - sum lgamma(x+1)
__device__ __forceinline__ void emis(const int4& xa, const int4& xb,
                                     const float* ll, float lamsum,
                                     const float* lgt, float& pe, float& gs) {
    float g = -lamsum;
    g = fmaf((float)xa.x, ll[0], g);
    g = fmaf((float)xa.y, ll[1], g);
    g = fmaf((float)xa.z, ll[2], g);
    g = fmaf((float)xa.w, ll[3], g);
    g = fmaf((float)xb.x, ll[4], g);
    g = fmaf((float)xb.y, ll[5], g);
    g = fmaf((float)xb.z, ll[6], g);
    g = fmaf((float)xb.w, ll[7], g);
    float Lt = lgt[xa.x] + lgt[xa.y] + lgt[xa.z] + lgt[xa.w] +
               lgt[xb.x] + lgt[xb.y] + lgt[xb.z] + lgt[xb.w];
    float gm = g;
#pragma unroll
    for (int m = 1; m <= 32; m <<= 1) gm = fmaxf(gm, __shfl_xor(gm, m, 64));
    pe = __expf(g - gm);
    gs = gm - Lt;
}

// loop emission: no lgamma (hoisted); gm_out = gmax only
__device__ __forceinline__ void emis_ng(const int4& xa, const int4& xb,
                                        const float* ll, float lamsum,
                                        float& pe, float& gm_out) {
    float g = -lamsum;
    g = fmaf((float)xa.x, ll[0], g);
    g = fmaf((float)xa.y, ll[1], g);
    g = fmaf((float)xa.z, ll[2], g);
    g = fmaf((float)xa.w, ll[3], g);
    g = fmaf((float)xb.x, ll[4], g);
    g = fmaf((float)xb.y, ll[5], g);
    g = fmaf((float)xb.z, ll[6], g);
    g = fmaf((float)xb.w, ll[7], g);
    float gm = g;
#pragma unroll
    for (int m = 1; m <= 32; m <<= 1) gm = fmaxf(gm, __shfl_xor(gm, m, 64));
    pe = __expf(g - gm);
    gm_out = gm;
}

// ---- fragment <-> memory helpers (map sigma; verified R4) ----

__device__ __forceinline__ void identity_B(bf16x8 B[2][4], int li, int q) {
#pragma unroll
    for (int kf = 0; kf < 2; ++kf)
#pragma unroll
        for (int nb = 0; nb < 4; ++nb) {
            int n = 16 * nb + li;
            u32x4 u;
#pragma unroll
            for (int wi = 0; wi < 4; ++wi) {
                int k0 = 32 * kf + 16 * (wi >> 1) + 4 * q + 2 * (wi & 1);
                uint32_t v = 0;
                if (k0 == n) v |= 0x3F80u;
                if (k0 + 1 == n) v |= 0x3F800000u;
                u[wi] = v;
            }
            B[kf][nb] = __builtin_bit_cast(bf16x8, u);
        }
}

// scatter state regs -> LDS row-major [k][n] pad RMP
__device__ __forceinline__ void state_to_rm(short* rm, const bf16x8 B[2][4],
                                            int li, int q) {
#pragma unroll
    for (int kf = 0; kf < 2; ++kf)
#pragma unroll
        for (int nb = 0; nb < 4; ++nb) {
            u32x4 u = __builtin_bit_cast(u32x4, B[kf][nb]);
            int n = 16 * nb + li;
#pragma unroll
            for (int wi = 0; wi < 4; ++wi) {
                int k0 = 32 * kf + 16 * (wi >> 1) + 4 * q + 2 * (wi & 1);
                uint32_t v = u[wi];
                rm[k0 * RMP + n] = (short)(v & 0xFFFFu);
                rm[(k0 + 1) * RMP + n] = (short)(v >> 16);
            }
        }
}

// scatter state regs -> GLOBAL row-major [k][n] stride 64
__device__ __forceinline__ void dump_rm_g(short* gm, const bf16x8 B[2][4],
                                          int li, int q) {
#pragma unroll
    for (int kf = 0; kf < 2; ++kf)
#pragma unroll
        for (int nb = 0; nb < 4; ++nb) {
            u32x4 u = __builtin_bit_cast(u32x4, B[kf][nb]);
            int n = 16 * nb + li;
#pragma unroll
            for (int wi = 0; wi < 4; ++wi) {
                int k0 = 32 * kf + 16 * (wi >> 1) + 4 * q + 2 * (wi & 1);
                uint32_t v = u[wi];
                gm[k0 * 64 + n] = (short)(v & 0xFFFFu);
                gm[(k0 + 1) * 64 + n] = (short)(v >> 16);
            }
        }
}

// read A-frags from LDS row-major [m][k] pad RMP
__device__ __forceinline__ void load_afrags(const short* rm, int li, int q,
                                            bf16x8 A[4][2]) {
#pragma unroll
    for (int mb = 0; mb < 4; ++mb)
#pragma unroll
        for (int kf = 0; kf < 2; ++kf) {
            const short* p = rm + (16 * mb + li) * RMP + 32 * kf + 4 * q;
            u32x2 lo = *(const u32x2*)p;
            u32x2 hi = *(const u32x2*)(p + 16);
            u32x4 u = {lo[0], lo[1], hi[0], hi[1]};
            A[mb][kf] = __builtin_bit_cast(bf16x8, u);
        }
}

// read A-frags from GLOBAL row-major [m][k] stride 64
__device__ __forceinline__ void load_afrags_g(const short* gm, int li, int q,
                                              bf16x8 A[4][2]) {
#pragma unroll
    for (int mb = 0; mb < 4; ++mb)
#pragma unroll
        for (int kf = 0; kf < 2; ++kf) {
            const short* p = gm + (16 * mb + li) * 64 + 32 * kf + 4 * q;
            u32x2 lo = *(const u32x2*)p;
            u32x2 hi = *(const u32x2*)(p + 16);
            u32x4 u = {lo[0], lo[1], hi[0], hi[1]};
            A[mb][kf] = __builtin_bit_cast(bf16x8, u);
        }
}

// B <- normalize(A*B); returns applied max. Caller logs it exactly.
__device__ __forceinline__ float leftmul(const bf16x8 A[4][2], bf16x8 B[2][4]) {
    f32x4 d[4][4];
#pragma unroll
    for (int mb = 0; mb < 4; ++mb)
#pragma unroll
        for (int nb = 0; nb < 4; ++nb) {
            f32x4 z = {0.f, 0.f, 0.f, 0.f};
            d[mb][nb] = MFMA(A[mb][0], B[0][nb], z);
            d[mb][nb] = MFMA(A[mb][1], B[1][nb], d[mb][nb]);
        }
    float pm = 0.f;
#pragma unroll
    for (int mb = 0; mb < 4; ++mb)
#pragma unroll
        for (int nb = 0; nb < 4; ++nb)
            pm = fmaxf(pm, fmaxf(fmaxf(d[mb][nb][0], d[mb][nb][1]),
                                 fmaxf(d[mb][nb][2], d[mb][nb][3])));
#pragma unroll
    for (int m = 1; m <= 32; m <<= 1) pm = fmaxf(pm, __shfl_xor(pm, m, 64));
    pm = fmaxf(pm, 1e-30f);
    float r = 1.0f / pm;
#pragma unroll
    for (int mb = 0; mb < 4; ++mb)
#pragma unroll
        for (int nb = 0; nb < 4; ++nb) {
#pragma unroll
            for (int reg = 0; reg < 4; ++reg)
                B[mb >> 1][nb][(mb & 1) * 4 + reg] =
                    (__bf16)(d[mb][nb][reg] * r);
        }
    return pm;
}

// One scan step (R6/R8-verified semantics, vectorized forms): BOUT <-
// diag(pe_s)*T*BIN / NRMV (2-lag rescale, exact f64 bookkeeping). pm on
// POST-scale values. Fragments assembled directly as u32x4 (cvt_pk), scales
// as f32x4 pk ops with r pre-folded. Pipelined emission s+1, x prefetch s+2.
#define STEP(BIN, BOUT, RS, WS, NRMV, GSC, GSN)                              \
    {                                                                        \
        int tn = t0 + s + 2;                                                 \
        tn = tn > TT - 1 ? TT - 1 : tn;                                      \
        int4 xan = *(const int4*)(x + (size_t)tn * MD);                      \
        int4 xbn = *(const int4*)(x + (size_t)tn * MD + 4);                  \
        float pe_n, gm_n;                                                    \
        emis_ng(xa1, xb1, ll, lamsum, pe_n, gm_n);                           \
        GSN = gm_n;                                                          \
        pes[WS][w][l] = pe_n;                                                \
        float r = 1.0f / NRMV;                                               \
        S += (double)GSC + (double)__logf(NRMV);                             \
        const float* pc = &pes[RS][w][0];                                    \
        f32x4 scv0 = *(const f32x4*)(pc + 4 * q) * r;                        \
        f32x4 scv1 = *(const f32x4*)(pc + 16 + 4 * q) * r;                   \
        f32x4 scv2 = *(const f32x4*)(pc + 32 + 4 * q) * r;                   \
        f32x4 scv3 = *(const f32x4*)(pc + 48 + 4 * q) * r;                   \
        f32x4 mx = {0.f, 0.f, 0.f, 0.f};                                     \
        _Pragma("unroll") for (int nb = 0; nb < 4; ++nb) {                   \
            f32x4 z = {0.f, 0.f, 0.f, 0.f};                                  \
            f32x4 d0 = MFMA(TA[0][0], BIN[0][nb], z);                        \
            d0 = MFMA(TA[0][1], BIN[1][nb], d0);                             \
            f32x4 d1 = MFMA(TA[1][0], BIN[0][nb], z);                        \
            d1 = MFMA(TA[1][1], BIN[1][nb], d1);                             \
            d0 *= scv0;                                                      \
            d1 *= scv1;                                                      \
            mx = __builtin_elementwise_max(mx, d0);                          \
            mx = __builtin_elementwise_max(mx, d1);                          \
            u32x4 u0 = {pk2(d0[0], d0[1]), pk2(d0[2], d0[3]),                \
                        pk2(d1[0], d1[1]), pk2(d1[2], d1[3])};               \
            BOUT[0][nb] = __builtin_bit_cast(bf16x8, u0);                    \
            f32x4 d2 = MFMA(TA[2][0], BIN[0][nb], z);                        \
            d2 = MFMA(TA[2][1], BIN[1][nb], d2);                             \
            f32x4 d3 = MFMA(TA[3][0], BIN[0][nb], z);                        \
            d3 = MFMA(TA[3][1], BIN[1][nb], d3);                             \
            d2 *= scv2;                                                      \
            d3 *= scv3;                                                      \
            mx = __builtin_elementwise_max(mx, d2);                          \
            mx = __builtin_elementwise_max(mx, d3);                          \
            u32x4 u1 = {pk2(d2[0], d2[1]), pk2(d2[2], d2[3]),                \
                        pk2(d3[0], d3[1]), pk2(d3[2], d3[3])};               \
            BOUT[1][nb] = __builtin_bit_cast(bf16x8, u1);                    \
        }                                                                    \
        float pm = fmaxf(fmaxf(mx[0], mx[1]), fmaxf(mx[2], mx[3]));          \
        _Pragma("unroll") for (int m = 1; m <= 32; m <<= 1)                  \
            pm = fmaxf(pm, __shfl_xor(pm, m, 64));                           \
        NRMV = fmaxf(pm, 1e-30f);                                            \
        xa1 = xan;                                                           \
        xb1 = xbn;                                                           \
        ++s;                                                                 \
    }

// ---------------- K1: per-chunk transfer-matrix product, in-register --------
__global__ __launch_bounds__(256, 2) void k_chunks(
    const int* __restrict__ x, const float* __restrict__ lambdas,
    const float* __restrict__ logT, short* __restrict__ M1,
    double* __restrict__ S1) {
    __shared__ short rm[4][64 * RMP];
    __shared__ float pes[2][4][64];
    __shared__ float lgt[20];
    __shared__ double Sw[4];
    const int tid = threadIdx.x;
    const int l = tid & 63, w = tid >> 6;
    const int li = l & 15, q = l >> 4;
    if (tid < 20) lgt[tid] = c_lg[tid];

    float ll[8];
    float lamsum = 0.f;
#pragma unroll
    for (int m = 0; m < 8; ++m) {
        float lam = lambdas[l * 8 + m];
        ll[m] = __logf(lam);
        lamsum += lam;
    }

    // constant A-frags of T: elem e of TA[mb][kf] = T[16mb+li][32kf+sigma(l,e)]
    bf16x8 TA[4][2];
#pragma unroll
    for (int mb = 0; mb < 4; ++mb)
#pragma unroll
        for (int kf = 0; kf < 2; ++kf) {
            const float* tp = logT + (16 * mb + li) * 64 + 32 * kf + 4 * q;
            float4 v0 = *(const float4*)tp;
            float4 v1 = *(const float4*)(tp + 16);
            bf16x8 a;
            a[0] = (__bf16)__expf(v0.x);
            a[1] = (__bf16)__expf(v0.y);
            a[2] = (__bf16)__expf(v0.z);
            a[3] = (__bf16)__expf(v0.w);
            a[4] = (__bf16)__expf(v1.x);
            a[5] = (__bf16)__expf(v1.y);
            a[6] = (__bf16)__expf(v1.z);
            a[7] = (__bf16)__expf(v1.w);
            TA[mb][kf] = a;
        }

    bf16x8 B0[2][4], B1[2][4];
    identity_B(B0, li, q);
    __syncthreads();  // lgt visible

    const int c = blockIdx.x * 4 + w;
    const int t0 = 1 + c * CHUNK;
    const int len = min(CHUNK, TT - t0);

    double S = 0.0;
    float nA = 1.0f, nBv = 1.0f;   // nrm ring: nrm_{s-2} (even/odd slots)
    float gsA = 0.f, gsB = 0.f;    // pipelined gmax ring
    int4 xa1, xb1;
    {
        int4 xa0 = *(const int4*)(x + (size_t)t0 * MD);
        int4 xb0 = *(const int4*)(x + (size_t)t0 * MD + 4);
        int t1 = t0 + 1 > TT - 1 ? TT - 1 : t0 + 1;
        xa1 = *(const int4*)(x + (size_t)t1 * MD);
        xb1 = *(const int4*)(x + (size_t)t1 * MD + 4);
        float pe0;
        emis_ng(xa0, xb0, ll, lamsum, pe0, gsA);
        pes[0][w][l] = pe0;
    }

    int s = 0;
    const int np = len >> 1;
#pragma unroll 1
    for (int p = 0; p < np; ++p) {
        STEP(B0, B1, 0, 1, nA, gsA, gsB);
        STEP(B1, B0, 1, 0, nBv, gsB, gsA);
    }
    if (len & 1) {
        STEP(B0, B1, 0, 1, nA, gsA, gsB);
#pragma unroll
        for (int kf = 0; kf < 2; ++kf)
#pragma unroll
            for (int nb = 0; nb < 4; ++nb) B0[kf][nb] = B1[kf][nb];
    }

    // hoisted lgamma: Sigma_t lgamma(x[t]+1), lane-parallel over t
    {
        float lt = 0.f;
        if (l < len) {
            const int4* xp = (const int4*)(x + (size_t)(t0 + l) * MD);
            int4 a = xp[0], b = xp[1];
            lt = lgt[a.x] + lgt[a.y] + lgt[a.z] + lgt[a.w] + lgt[b.x] +
                 lgt[b.y] + lgt[b.z] + lgt[b.w];
        }
#pragma unroll
        for (int m = 1; m <= 32; m <<= 1) lt += __shfl_xor(lt, m, 64);
        S -= (double)lt;
    }

    // ---- block combine: product = M3*M2*M1*M0, dump row-major ----
    if (w) state_to_rm(&rm[w][0], B0, li, q);
    if (l == 0) Sw[w] = S;
    __syncthreads();
    if (w == 0) {
#pragma unroll 1
        for (int j = 1; j < 4; ++j) {
            bf16x8 A[4][2];
            load_afrags(&rm[j][0], li, q, A);
            float pm = leftmul(A, B0);
            S += Sw[j] + (double)__logf(pm);
        }
        dump_rm_g(M1 + (size_t)blockIdx.x * 4096, B0, li, q);
        if (l == 0) S1[blockIdx.x] = S;
    }
}

// ---------------- K2: fold 1024 -> 32 (prefetched serial folds) -------------
__global__ __launch_bounds__(256, 1) void k_combine(
    const short* __restrict__ M1, const double* __restrict__ S1,
    short* __restrict__ M2, double* __restrict__ S2) {
    __shared__ short rm[4][64 * RMP];
    __shared__ double Sw[4];
    const int tid = threadIdx.x;
    const int l = tid & 63, w = tid >> 6;
    const int li = l & 15, q = l >> 4;
    const int base = (blockIdx.x * 4 + w) * 8;

    bf16x8 B[2][4];
    identity_B(B, li, q);
    double S = 0.0;
    bf16x8 Aa[4][2], Ab[4][2];
    load_afrags_g(M1 + (size_t)base * 4096, li, q, Aa);
#pragma unroll
    for (int j = 0; j < 8; j += 2) {
        load_afrags_g(M1 + (size_t)(base + j + 1) * 4096, li, q, Ab);
        float pm = leftmul(Aa, B);
        S += S1[base + j] + (double)__logf(pm);
        if (j + 2 < 8)
            load_afrags_g(M1 + (size_t)(base + j + 2) * 4096, li, q, Aa);
        pm = leftmul(Ab, B);
        S += S1[base + j + 1] + (double)__logf(pm);
    }

    if (w) state_to_rm(&rm[w][0], B, li, q);
    if (l == 0) Sw[w] = S;
    __syncthreads();
    if (w == 0) {
#pragma unroll 1
        for (int j = 1; j < 4; ++j) {
            bf16x8 A[4][2];
            load_afrags(&rm[j][0], li, q, A);
            float pm = leftmul(A, B);
            S += Sw[j] + (double)__logf(pm);
        }
        dump_rm_g(M2 + (size_t)blockIdx.x * 4096, B, li, q);
        if (l == 0) S2[blockIdx.x] = S;
    }
}

// ---------------- K3: fold 32 -> 1, alpha0, final LSE ------------------------
__global__ __launch_bounds__(256, 1) void k_final(
    const int* __restrict__ x, const float* __restrict__ lambdas,
    const float* __restrict__ prior, const short* __restrict__ M2,
    const double* __restrict__ S2, float* __restrict__ out) {
    __shared__ short rm[4][64 * RMP];
    __shared__ double Sw[4];
    __shared__ float lgt[20];
    const int tid = threadIdx.x;
    const int l = tid & 63, w = tid >> 6;
    const int li = l & 15, q = l >> 4;
    if (tid < 20) lgt[tid] = c_lg[tid];
    __syncthreads();

    const int base = w * 8;
    bf16x8 B[2][4];
    identity_B(B, li, q);
    double S = 0.0;
    bf16x8 Aa[4][2], Ab[4][2];
    load_afrags_g(M2 + (size_t)base * 4096, li, q, Aa);
#pragma unroll
    for (int j = 0; j < 8; j += 2) {
        load_afrags_g(M2 + (size_t)(base + j + 1) * 4096, li, q, Ab);
        float pm = leftmul(Aa, B);
        S += S2[base + j] + (double)__logf(pm);
        if (j + 2 < 8)
            load_afrags_g(M2 + (size_t)(base + j + 2) * 4096, li, q, Aa);
        pm = leftmul(Ab, B);
        S += S2[base + j + 1] + (double)__logf(pm);
    }

    if (w) state_to_rm(&rm[w][0], B, li, q);
    if (l == 0) Sw[w] = S;
    __syncthreads();
    if (w == 0) {
#pragma unroll 1
        for (int j = 1; j < 4; ++j) {
            bf16x8 A[4][2];
            load_afrags(&rm[j][0], li, q, A);
            float pm = leftmul(A, B);
            S += Sw[j] + (double)__logf(pm);
        }
        // finalize: alpha0 = em_0 * exp(prior); total = 1^T B alpha0
        float ll[8];
        float lamsum = 0.f;
#pragma unroll
        for (int m = 0; m < 8; ++m) {
            float lam = lambdas[l * 8 + m];
            ll[m] = __logf(lam);
            lamsum += lam;
        }
        int4 xa = *(const int4*)(x);
        int4 xb = *(const int4*)(x + 4);
        float pe0, gs0;
        emis(xa, xb, ll, lamsum, lgt, pe0, gs0);
        S += (double)gs0;
        float a0 = pe0 * __expf(prior[l]);

        float av[4];
#pragma unroll
        for (int nb = 0; nb < 4; ++nb) av[nb] = __shfl(a0, 16 * nb + li, 64);

        float acc = 0.f;
#pragma unroll
        for (int kf = 0; kf < 2; ++kf)
#pragma unroll
            for (int nb = 0; nb < 4; ++nb) {
                u32x4 u = __builtin_bit_cast(u32x4, B[kf][nb]);
#pragma unroll
                for (int e = 0; e < 4; ++e) {
                    float flo = __builtin_bit_cast(float, u[e] << 16);
                    float fhi = __builtin_bit_cast(float, u[e] & 0xFFFF0000u);
                    acc = fmaf(flo + fhi, av[nb], acc);
                }
            }
#pragma unroll
        for (int m = 1; m <= 32; m <<= 1) acc += __shfl_xor(acc, m, 64);
        if (l == 0) out[0] = (float)(S + (double)__logf(acc));
    }
}

extern "C" void kernel_launch(void* const* d_in, const int* in_sizes, int n_in,
                              void* d_out, int out_size, void* d_ws,
                              size_t ws_size, hipStream_t stream) {
    const int* x = (const int*)d_in[0];
    const float* lambdas = (const float*)d_in[1];
    const float* logT = (const float*)d_in[2];
    const float* prior = (const float*)d_in[3];
    float* out = (float*)d_out;
    char* ws = (char*)d_ws;
    // ws layout (~8.66 MB): M1 1024*4096*2B, S1 1024*8B, M2 32*4096*2B, S2 32*8B
    short* M1 = (short*)ws;
    double* S1 = (double*)(ws + 8388608);
    short* M2 = (short*)(ws + 8396800);
    double* S2 = (double*)(ws + 8658944);

    k_chunks<<<NCH, 256, 0, stream>>>(x, lambdas, logT, M1, S1);
    k_combine<<<32, 256, 0, stream>>>(M1, S1, M2, S2);
    k_final<<<1, 256, 0, stream>>>(x, lambdas, prior, M2, S2, out);
}

// Round 10
// 145.134 us; speedup vs baseline: 1.1020x; 1.0048x over previous
//
#include <hip/hip_runtime.h>
#include <stdint.h>

#define TT 131072
#define MD 8
#define CHUNK 32
#define NCH 1024
#define RMP 72   // row-major LDS pad (shorts per row)

using f32x4  = __attribute__((ext_vector_type(4))) float;
using bf16x8 = __attribute__((ext_vector_type(8))) __bf16;
using bf16x2 = __attribute__((ext_vector_type(2))) __bf16;
using u32x2  = __attribute__((ext_vector_type(2))) uint32_t;
using u32x4  = __attribute__((ext_vector_type(4))) uint32_t;

// log(n!) for n = 0..19 (x in [0,20))
__device__ __constant__ float c_lg[20] = {
    0.0f, 0.0f, 0.69314718f, 1.79175947f, 3.17805383f,
    4.78749174f, 6.57925121f, 8.52516136f, 10.60460290f, 12.80182748f,
    15.10441257f, 17.50230785f, 19.98721386f, 22.55216385f, 25.19122118f,
    27.89927138f, 30.67186011f, 33.50507345f, 36.39544521f, 39.33988419f};

#define MFMA(a, b, c) __builtin_amdgcn_mfma_f32_16x16x32_bf16((a), (b), (c), 0, 0, 0)

// pack two f32 -> one u32 of 2 bf16 (RNE; compiler emits v_cvt_pk_bf16_f32)
__device__ __forceinline__ uint32_t pk2(float lo, float hi) {
    bf16x2 t = {(__bf16)lo, (__bf16)hi};
    return __builtin_bit_cast(uint32_t, t);
}

// Bookkeeping fragment map sigma (consistent everywhere; HW map may differ —
// it cancels): frag elem e of a K=32 operand covers k = 16*(e>>2) + 4*q + (e&3),
// q = lane>>4; A rows / B cols on lane&15. State B[kf][nb] holds
// M[32kf + sigma(l,e)][16nb + (l&15)].

// full emission (K3 only): pe = exp(g-gmax), gs = gmax - sum lgamma(x+1)
__device__ __forceinline__ void emis(const int4& xa, const int4& xb,
                                     const float* ll, float lamsum,
                                     const float* lgt, float& pe, float& gs) {
    float g = -lamsum;
    g = fmaf((float)xa.x, ll[0], g);
    g = fmaf((float)xa.y, ll[1], g);
    g = fmaf((float)xa.z, ll[2], g);
    g = fmaf((float)xa.w, ll[3], g);
    g = fmaf((float)xb.x, ll[4], g);
    g = fmaf((float)xb.y, ll[5], g);
    g = fmaf((float)xb.z, ll[6], g);
    g = fmaf((float)xb.w, ll[7], g);
    float Lt = lgt[xa.x] + lgt[xa.y] + lgt[xa.z] + lgt[xa.w] +
               lgt[xb.x] + lgt[xb.y] + lgt[xb.z] + lgt[xb.w];
    float gm = g;
#pragma unroll
    for (int m = 1; m <= 32; m <<= 1) gm = fmaxf(gm, __shfl_xor(gm, m, 64));
    pe = __expf(g - gm);
    gs = gm - Lt;
}

// loop emission: no lgamma (hoisted); gm_out = gmax only
__device__ __forceinline__ void emis_ng(const int4& xa, const int4& xb,
                                        const float* ll, float lamsum,
                                        float& pe, float& gm_out) {
    float g = -lamsum;
    g = fmaf((float)xa.x, ll[0], g);
    g = fmaf((float)xa.y, ll[1], g);
    g = fmaf((float)xa.z, ll[2], g);
    g = fmaf((float)xa.w, ll[3], g);
    g = fmaf((float)xb.x, ll[4], g);
    g = fmaf((float)xb.y, ll[5], g);
    g = fmaf((float)xb.z, ll[6], g);
    g = fmaf((float)xb.w, ll[7], g);
    float gm = g;
#pragma unroll
    for (int m = 1; m <= 32; m <<= 1) gm = fmaxf(gm, __shfl_xor(gm, m, 64));
    pe = __expf(g - gm);
    gm_out = gm;
}

// ---- fragment <-> memory helpers (map sigma; verified R4) ----

__device__ __forceinline__ void identity_B(bf16x8 B[2][4], int li, int q) {
#pragma unroll
    for (int kf = 0; kf < 2; ++kf)
#pragma unroll
        for (int nb = 0; nb < 4; ++nb) {
            int n = 16 * nb + li;
            u32x4 u;
#pragma unroll
            for (int wi = 0; wi < 4; ++wi) {
                int k0 = 32 * kf + 16 * (wi >> 1) + 4 * q + 2 * (wi & 1);
                uint32_t v = 0;
                if (k0 == n) v |= 0x3F80u;
                if (k0 + 1 == n) v |= 0x3F800000u;
                u[wi] = v;
            }
            B[kf][nb] = __builtin_bit_cast(bf16x8, u);
        }
}

// scatter state regs -> LDS row-major [k][n] pad RMP
__device__ __forceinline__ void state_to_rm(short* rm, const bf16x8 B[2][4],
                                            int li, int q) {
#pragma unroll
    for (int kf = 0; kf < 2; ++kf)
#pragma unroll
        for (int nb = 0; nb < 4; ++nb) {
            u32x4 u = __builtin_bit_cast(u32x4, B[kf][nb]);
            int n = 16 * nb + li;
#pragma unroll
            for (int wi = 0; wi < 4; ++wi) {
                int k0 = 32 * kf + 16 * (wi >> 1) + 4 * q + 2 * (wi & 1);
                uint32_t v = u[wi];
                rm[k0 * RMP + n] = (short)(v & 0xFFFFu);
                rm[(k0 + 1) * RMP + n] = (short)(v >> 16);
            }
        }
}

// scatter state regs -> GLOBAL row-major [k][n] stride 64
__device__ __forceinline__ void dump_rm_g(short* gm, const bf16x8 B[2][4],
                                          int li, int q) {
#pragma unroll
    for (int kf = 0; kf < 2; ++kf)
#pragma unroll
        for (int nb = 0; nb < 4; ++nb) {
            u32x4 u = __builtin_bit_cast(u32x4, B[kf][nb]);
            int n = 16 * nb + li;
#pragma unroll
            for (int wi = 0; wi < 4; ++wi) {
                int k0 = 32 * kf + 16 * (wi >> 1) + 4 * q + 2 * (wi & 1);
                uint32_t v = u[wi];
                gm[k0 * 64 + n] = (short)(v & 0xFFFFu);
                gm[(k0 + 1) * 64 + n] = (short)(v >> 16);
            }
        }
}

// read A-frags from LDS row-major [m][k] pad RMP
__device__ __forceinline__ void load_afrags(const short* rm, int li, int q,
                                            bf16x8 A[4][2]) {
#pragma unroll
    for (int mb = 0; mb < 4; ++mb)
#pragma unroll
        for (int kf = 0; kf < 2; ++kf) {
            const short* p = rm + (16 * mb + li) * RMP + 32 * kf + 4 * q;
            u32x2 lo = *(const u32x2*)p;
            u32x2 hi = *(const u32x2*)(p + 16);
            u32x4 u = {lo[0], lo[1], hi[0], hi[1]};
            A[mb][kf] = __builtin_bit_cast(bf16x8, u);
        }
}

// read A-frags from GLOBAL row-major [m][k] stride 64
__device__ __forceinline__ void load_afrags_g(const short* gm, int li, int q,
                                              bf16x8 A[4][2]) {
#pragma unroll
    for (int mb = 0; mb < 4; ++mb)
#pragma unroll
        for (int kf = 0; kf < 2; ++kf) {
            const short* p = gm + (16 * mb + li) * 64 + 32 * kf + 4 * q;
            u32x2 lo = *(const u32x2*)p;
            u32x2 hi = *(const u32x2*)(p + 16);
            u32x4 u = {lo[0], lo[1], hi[0], hi[1]};
            A[mb][kf] = __builtin_bit_cast(bf16x8, u);
        }
}

// B <- normalize(A*B); returns applied max. Caller logs it exactly.
__device__ __forceinline__ float leftmul(const bf16x8 A[4][2], bf16x8 B[2][4]) {
    f32x4 d[4][4];
#pragma unroll
    for (int mb = 0; mb < 4; ++mb)
#pragma unroll
        for (int nb = 0; nb < 4; ++nb) {
            f32x4 z = {0.f, 0.f, 0.f, 0.f};
            d[mb][nb] = MFMA(A[mb][0], B[0][nb], z);
            d[mb][nb] = MFMA(A[mb][1], B[1][nb], d[mb][nb]);
        }
    float pm = 0.f;
#pragma unroll
    for (int mb = 0; mb < 4; ++mb)
#pragma unroll
        for (int nb = 0; nb < 4; ++nb)
            pm = fmaxf(pm, fmaxf(fmaxf(d[mb][nb][0], d[mb][nb][1]),
                                 fmaxf(d[mb][nb][2], d[mb][nb][3])));
#pragma unroll
    for (int m = 1; m <= 32; m <<= 1) pm = fmaxf(pm, __shfl_xor(pm, m, 64));
    pm = fmaxf(pm, 1e-30f);
    float r = 1.0f / pm;
#pragma unroll
    for (int mb = 0; mb < 4; ++mb)
#pragma unroll
        for (int nb = 0; nb < 4; ++nb) {
#pragma unroll
            for (int reg = 0; reg < 4; ++reg)
                B[mb >> 1][nb][(mb & 1) * 4 + reg] =
                    (__bf16)(d[mb][nb][reg] * r);
        }
    return pm;
}

// One scan step (R6/R8-verified semantics, vectorized forms): BOUT <-
// diag(pe_s)*T*BIN / NRMV (2-lag rescale, exact f64 bookkeeping). pm on
// POST-scale values. Fragments assembled directly as u32x4 (cvt_pk), scales
// as f32x4 pk ops with r pre-folded. Pipelined emission s+1, x prefetch s+2.
#define STEP(BIN, BOUT, RS, WS, NRMV, GSC, GSN)                              \
    {                                                                        \
        int tn = t0 + s + 2;                                                 \
        tn = tn > TT - 1 ? TT - 1 : tn;                                      \
        int4 xan = *(const int4*)(x + (size_t)tn * MD);                      \
        int4 xbn = *(const int4*)(x + (size_t)tn * MD + 4);                  \
        float pe_n, gm_n;                                                    \
        emis_ng(xa1, xb1, ll, lamsum, pe_n, gm_n);                           \
        GSN = gm_n;                                                          \
        pes[WS][w][l] = pe_n;                                                \
        float r = 1.0f / NRMV;                                               \
        S += (double)GSC + (double)__logf(NRMV);                             \
        const float* pc = &pes[RS][w][0];                                    \
        f32x4 scv0 = *(const f32x4*)(pc + 4 * q) * r;                        \
        f32x4 scv1 = *(const f32x4*)(pc + 16 + 4 * q) * r;                   \
        f32x4 scv2 = *(const f32x4*)(pc + 32 + 4 * q) * r;                   \
        f32x4 scv3 = *(const f32x4*)(pc + 48 + 4 * q) * r;                   \
        f32x4 mx = {0.f, 0.f, 0.f, 0.f};                                     \
        _Pragma("unroll") for (int nb = 0; nb < 4; ++nb) {                   \
            f32x4 z = {0.f, 0.f, 0.f, 0.f};                                  \
            f32x4 d0 = MFMA(TA[0][0], BIN[0][nb], z);                        \
            d0 = MFMA(TA[0][1], BIN[1][nb], d0);                             \
            f32x4 d1 = MFMA(TA[1][0], BIN[0][nb], z);                        \
            d1 = MFMA(TA[1][1], BIN[1][nb], d1);                             \
            d0 *= scv0;                                                      \
            d1 *= scv1;                                                      \
            mx = __builtin_elementwise_max(mx, d0);                          \
            mx = __builtin_elementwise_max(mx, d1);                          \
            u32x4 u0 = {pk2(d0[0], d0[1]), pk2(d0[2], d0[3]),                \
                        pk2(d1[0], d1[1]), pk2(d1[2], d1[3])};               \
            BOUT[0][nb] = __builtin_bit_cast(bf16x8, u0);                    \
            f32x4 d2 = MFMA(TA[2][0], BIN[0][nb], z);                        \
            d2 = MFMA(TA[2][1], BIN[1][nb], d2);                             \
            f32x4 d3 = MFMA(TA[3][0], BIN[0][nb], z);                        \
            d3 = MFMA(TA[3][1], BIN[1][nb], d3);                             \
            d2 *= scv2;                                                      \
            d3 *= scv3;                                                      \
            mx = __builtin_elementwise_max(mx, d2);                          \
            mx = __builtin_elementwise_max(mx, d3);                          \
            u32x4 u1 = {pk2(d2[0], d2[1]), pk2(d2[2], d2[3]),                \
                        pk2(d3[0], d3[1]), pk2(d3[2], d3[3])};               \
            BOUT[1][nb] = __builtin_bit_cast(bf16x8, u1);                    \
        }                                                                    \
        float pm = fmaxf(fmaxf(mx[0], mx[1]), fmaxf(mx[2], mx[3]));          \
        _Pragma("unroll") for (int m = 1; m <= 32; m <<= 1)                  \
            pm = fmaxf(pm, __shfl_xor(pm, m, 64));                           \
        NRMV = fmaxf(pm, 1e-30f);                                            \
        xa1 = xan;                                                           \
        xb1 = xbn;                                                           \
        ++s;                                                                 \
    }

// ---------------- K1: per-chunk transfer-matrix product, in-register --------
// LDS ~29.8 KB (rm[3]) so 4 blocks/CU fit; launch_bounds(256,4) -> 4 waves/EU.
__global__ __launch_bounds__(256, 4) void k_chunks(
    const int* __restrict__ x, const float* __restrict__ lambdas,
    const float* __restrict__ logT, short* __restrict__ M1,
    double* __restrict__ S1) {
    __shared__ short rm[3][64 * RMP];
    __shared__ float pes[2][4][64];
    __shared__ float lgt[20];
    __shared__ double Sw[4];
    const int tid = threadIdx.x;
    const int l = tid & 63, w = tid >> 6;
    const int li = l & 15, q = l >> 4;
    if (tid < 20) lgt[tid] = c_lg[tid];

    float ll[8];
    float lamsum = 0.f;
#pragma unroll
    for (int m = 0; m < 8; ++m) {
        float lam = lambdas[l * 8 + m];
        ll[m] = __logf(lam);
        lamsum += lam;
    }

    // constant A-frags of T: elem e of TA[mb][kf] = T[16mb+li][32kf+sigma(l,e)]
    bf16x8 TA[4][2];
#pragma unroll
    for (int mb = 0; mb < 4; ++mb)
#pragma unroll
        for (int kf = 0; kf < 2; ++kf) {
            const float* tp = logT + (16 * mb + li) * 64 + 32 * kf + 4 * q;
            float4 v0 = *(const float4*)tp;
            float4 v1 = *(const float4*)(tp + 16);
            bf16x8 a;
            a[0] = (__bf16)__expf(v0.x);
            a[1] = (__bf16)__expf(v0.y);
            a[2] = (__bf16)__expf(v0.z);
            a[3] = (__bf16)__expf(v0.w);
            a[4] = (__bf16)__expf(v1.x);
            a[5] = (__bf16)__expf(v1.y);
            a[6] = (__bf16)__expf(v1.z);
            a[7] = (__bf16)__expf(v1.w);
            TA[mb][kf] = a;
        }

    bf16x8 B0[2][4], B1[2][4];
    identity_B(B0, li, q);
    __syncthreads();  // lgt visible

    const int c = blockIdx.x * 4 + w;
    const int t0 = 1 + c * CHUNK;
    const int len = min(CHUNK, TT - t0);

    double S = 0.0;
    float nA = 1.0f, nBv = 1.0f;   // nrm ring: nrm_{s-2} (even/odd slots)
    float gsA = 0.f, gsB = 0.f;    // pipelined gmax ring
    int4 xa1, xb1;
    {
        int4 xa0 = *(const int4*)(x + (size_t)t0 * MD);
        int4 xb0 = *(const int4*)(x + (size_t)t0 * MD + 4);
        int t1 = t0 + 1 > TT - 1 ? TT - 1 : t0 + 1;
        xa1 = *(const int4*)(x + (size_t)t1 * MD);
        xb1 = *(const int4*)(x + (size_t)t1 * MD + 4);
        float pe0;
        emis_ng(xa0, xb0, ll, lamsum, pe0, gsA);
        pes[0][w][l] = pe0;
    }

    int s = 0;
    const int np = len >> 1;
#pragma unroll 1
    for (int p = 0; p < np; ++p) {
        STEP(B0, B1, 0, 1, nA, gsA, gsB);
        STEP(B1, B0, 1, 0, nBv, gsB, gsA);
    }
    if (len & 1) {
        STEP(B0, B1, 0, 1, nA, gsA, gsB);
#pragma unroll
        for (int kf = 0; kf < 2; ++kf)
#pragma unroll
            for (int nb = 0; nb < 4; ++nb) B0[kf][nb] = B1[kf][nb];
    }

    // hoisted lgamma: Sigma_t lgamma(x[t]+1), lane-parallel over t
    {
        float lt = 0.f;
        if (l < len) {
            const int4* xp = (const int4*)(x + (size_t)(t0 + l) * MD);
            int4 a = xp[0], b = xp[1];
            lt = lgt[a.x] + lgt[a.y] + lgt[a.z] + lgt[a.w] + lgt[b.x] +
                 lgt[b.y] + lgt[b.z] + lgt[b.w];
        }
#pragma unroll
        for (int m = 1; m <= 32; m <<= 1) lt += __shfl_xor(lt, m, 64);
        S -= (double)lt;
    }

    // ---- block combine: product = M3*M2*M1*M0, dump row-major ----
    if (w) state_to_rm(&rm[w - 1][0], B0, li, q);
    if (l == 0) Sw[w] = S;
    __syncthreads();
    if (w == 0) {
#pragma unroll 1
        for (int j = 1; j < 4; ++j) {
            bf16x8 A[4][2];
            load_afrags(&rm[j - 1][0], li, q, A);
            float pm = leftmul(A, B0);
            S += Sw[j] + (double)__logf(pm);
        }
        dump_rm_g(M1 + (size_t)blockIdx.x * 4096, B0, li, q);
        if (l == 0) S1[blockIdx.x] = S;
    }
}

// ---------------- K2: fold 1024 -> 32 (prefetched serial folds) -------------
__global__ __launch_bounds__(256, 1) void k_combine(
    const short* __restrict__ M1, const double* __restrict__ S1,
    short* __restrict__ M2, double* __restrict__ S2) {
    __shared__ short rm[3][64 * RMP];
    __shared__ double Sw[4];
    const int tid = threadIdx.x;
    const int l = tid & 63, w = tid >> 6;
    const int li = l & 15, q = l >> 4;
    const int base = (blockIdx.x * 4 + w) * 8;

    bf16x8 B[2][4];
    identity_B(B, li, q);
    double S = 0.0;
    bf16x8 Aa[4][2], Ab[4][2];
    load_afrags_g(M1 + (size_t)base * 4096, li, q, Aa);
#pragma unroll
    for (int j = 0; j < 8; j += 2) {
        load_afrags_g(M1 + (size_t)(base + j + 1) * 4096, li, q, Ab);
        float pm = leftmul(Aa, B);
        S += S1[base + j] + (double)__logf(pm);
        if (j + 2 < 8)
            load_afrags_g(M1 + (size_t)(base + j + 2) * 4096, li, q, Aa);
        pm = leftmul(Ab, B);
        S += S1[base + j + 1] + (double)__logf(pm);
    }

    if (w) state_to_rm(&rm[w - 1][0], B, li, q);
    if (l == 0) Sw[w] = S;
    __syncthreads();
    if (w == 0) {
#pragma unroll 1
        for (int j = 1; j < 4; ++j) {
            bf16x8 A[4][2];
            load_afrags(&rm[j - 1][0], li, q, A);
            float pm = leftmul(A, B);
            S += Sw[j] + (double)__logf(pm);
        }
        dump_rm_g(M2 + (size_t)blockIdx.x * 4096, B, li, q);
        if (l == 0) S2[blockIdx.x] = S;
    }
}

// ---------------- K3: fold 32 -> 1, alpha0, final LSE ------------------------
__global__ __launch_bounds__(256, 1) void k_final(
    const int* __restrict__ x, const float* __restrict__ lambdas,
    const float* __restrict__ prior, const short* __restrict__ M2,
    const double* __restrict__ S2, float* __restrict__ out) {
    __shared__ short rm[3][64 * RMP];
    __shared__ double Sw[4];
    __shared__ float lgt[20];
    const int tid = threadIdx.x;
    const int l = tid & 63, w = tid >> 6;
    const int li = l & 15, q = l >> 4;
    if (tid < 20) lgt[tid] = c_lg[tid];
    __syncthreads();

    const int base = w * 8;
    bf16x8 B[2][4];
    identity_B(B, li, q);
    double S = 0.0;
    bf16x8 Aa[4][2], Ab[4][2];
    load_afrags_g(M2 + (size_t)base * 4096, li, q, Aa);
#pragma unroll
    for (int j = 0; j < 8; j += 2) {
        load_afrags_g(M2 + (size_t)(base + j + 1) * 4096, li, q, Ab);
        float pm = leftmul(Aa, B);
        S += S2[base + j] + (double)__logf(pm);
        if (j + 2 < 8)
            load_afrags_g(M2 + (size_t)(base + j + 2) * 4096, li, q, Aa);
        pm = leftmul(Ab, B);
        S += S2[base + j + 1] + (double)__logf(pm);
    }

    if (w) state_to_rm(&rm[w - 1][0], B, li, q);
    if (l == 0) Sw[w] = S;
    __syncthreads();
    if (w == 0) {
#pragma unroll 1
        for (int j = 1; j < 4; ++j) {
            bf16x8 A[4][2];
            load_afrags(&rm[j - 1][0], li, q, A);
            float pm = leftmul(A, B);
            S += Sw[j] + (double)__logf(pm);
        }
        // finalize: alpha0 = em_0 * exp(prior); total = 1^T B alpha0
        float ll[8];
        float lamsum = 0.f;
#pragma unroll
        for (int m = 0; m < 8; ++m) {
            float lam = lambdas[l * 8 + m];
            ll[m] = __logf(lam);
            lamsum += lam;
        }
        int4 xa = *(const int4*)(x);
        int4 xb = *(const int4*)(x + 4);
        float pe0, gs0;
        emis(xa, xb, ll, lamsum, lgt, pe0, gs0);
        S += (double)gs0;
        float a0 = pe0 * __expf(prior[l]);

        float av[4];
#pragma unroll
        for (int nb = 0; nb < 4; ++nb) av[nb] = __shfl(a0, 16 * nb + li, 64);

        float acc = 0.f;
#pragma unroll
        for (int kf = 0; kf < 2; ++kf)
#pragma unroll
            for (int nb = 0; nb < 4; ++nb) {
                u32x4 u = __builtin_bit_cast(u32x4, B[kf][nb]);
#pragma unroll
                for (int e = 0; e < 4; ++e) {
                    float flo = __builtin_bit_cast(float, u[e] << 16);
                    float fhi = __builtin_bit_cast(float, u[e] & 0xFFFF0000u);
                    acc = fmaf(flo + fhi, av[nb], acc);
                }
            }
#pragma unroll
        for (int m = 1; m <= 32; m <<= 1) acc += __shfl_xor(acc, m, 64);
        if (l == 0) out[0] = (float)(S + (double)__logf(acc));
    }
}

extern "C" void kernel_launch(void* const* d_in, const int* in_sizes, int n_in,
                              void* d_out, int out_size, void* d_ws,
                              size_t ws_size, hipStream_t stream) {
    const int* x = (const int*)d_in[0];
    const float* lambdas = (const float*)d_in[1];
    const float* logT = (const float*)d_in[2];
    const float* prior = (const float*)d_in[3];
    float* out = (float*)d_out;
    char* ws = (char*)d_ws;
    // ws layout (~8.66 MB): M1 1024*4096*2B, S1 1024*8B, M2 32*4096*2B, S2 32*8B
    short* M1 = (short*)ws;
    double* S1 = (double*)(ws + 8388608);
    short* M2 = (short*)(ws + 8396800);
    double* S2 = (double*)(ws + 8658944);

    k_chunks<<<NCH, 256, 0, stream>>>(x, lambdas, logT, M1, S1);
    k_combine<<<32, 256, 0, stream>>>(M1, S1, M2, S2);
    k_final<<<1, 256, 0, stream>>>(x, lambdas, prior, M2, S2, out);
}